// Round 2
// baseline (308.496 us; speedup 1.0000x reference)
//
#include <hip/hip_runtime.h>
#include <hip/hip_bf16.h>

// Problem constants (SelectSphereConv, graph level 6)
#define VN 40962
#define BN 4
#define CN 64
#define KN 9
#define ON 64
#define KK 576            // CN*KN, GEMM reduction dim
#define NKS 18            // KK/32 K-steps for 16x16x32 MFMA
#define NV 8              // vertices per block-group
#define NGROUPS 5121      // ceil(VN/NV)
#define GRID_FUSED 1024   // 4 blocks/CU * 256 CU  (LDS allows exactly 4)
#define LDA_B 1168        // A_lds row stride bytes: 576*2 + 16 pad (16B-aligned, balanced banks for b128)

typedef float f32x4 __attribute__((ext_vector_type(4)));
typedef float f32x2 __attribute__((ext_vector_type(2)));
typedef __bf16 bf16x8 __attribute__((ext_vector_type(8)));
typedef __bf16 bf16x2 __attribute__((ext_vector_type(2)));

// ---------------------------------------------------------------------------
// Kernel 1: transpose x [256(t=b*64+c), V] f32 -> x_t [V, 256] bf16
// ---------------------------------------------------------------------------
__global__ __launch_bounds__(256) void k_transpose(const float* __restrict__ x,
                                                   __bf16* __restrict__ xt) {
    __shared__ __bf16 tile[64][65];
    const int v0 = blockIdx.x * 64;
    const int t0 = blockIdx.y * 64;
    const int lane = threadIdx.x & 63;
    const int sub = threadIdx.x >> 6;  // 0..3

#pragma unroll
    for (int r = 0; r < 16; ++r) {
        const int t = t0 + r * 4 + sub;
        const int v = v0 + lane;
        float val = (v < VN) ? x[(size_t)t * VN + v] : 0.f;  // coalesced 256B/wave
        tile[r * 4 + sub][lane] = (__bf16)val;
    }
    __syncthreads();
#pragma unroll
    for (int r = 0; r < 16; ++r) {
        const int vv = r * 4 + sub;
        const int v = v0 + vv;
        if (v < VN) xt[(size_t)v * 256 + t0 + lane] = tile[lane][vv];  // coalesced 128B/wave
    }
}

// ---------------------------------------------------------------------------
// Kernel 2: fused gather + interpolate (VALU) + conv (MFMA)
//   Phase 1: wave w owns vertices {2w, 2w+1}; 64 lanes cover one x_t row
//            (lane loads t = lane*4 .. lane*4+3, processed in 2 halves to
//             bound register pressure). Writes contiguous 72B per lane.
//   A-tile rows: r = vv*4 + b (32 rows); K: c*9+j (matches conv_w layout)
//   Phase 2: one 16-col tile per wave, W fragments held in registers.
// ---------------------------------------------------------------------------
__global__ __launch_bounds__(256, 4) void k_fused(const __bf16* __restrict__ xt,
                                                  const int* __restrict__ index,
                                                  const float* __restrict__ itp_mat,
                                                  const float* __restrict__ conv_w,
                                                  const float* __restrict__ conv_b,
                                                  float* __restrict__ out) {
    __shared__ char smem[32 * LDA_B];  // 37376 B: A-tile, reused as C staging

    const int tid  = threadIdx.x;
    const int lane = tid & 63;
    const int wave = tid >> 6;
    const int l16  = lane & 15;
    const int g4   = lane >> 4;     // 0..3
    const int kb   = g4 * 8;        // k-base within a 32-wide K-step

    // ---- W fragments in registers: 18 ksteps x 8 bf16 = 72 VGPR ----
    bf16x8 wfrag[NKS];
    {
        const int o = wave * 16 + l16;
        const float* wrow = conv_w + (size_t)o * KK;
#pragma unroll
        for (int ks = 0; ks < NKS; ++ks) {
            f32x4 w0 = *(const f32x4*)(wrow + ks * 32 + kb);
            f32x4 w1 = *(const f32x4*)(wrow + ks * 32 + kb + 4);
            bf16x8 f;
            f[0] = (__bf16)w0[0]; f[1] = (__bf16)w0[1];
            f[2] = (__bf16)w0[2]; f[3] = (__bf16)w0[3];
            f[4] = (__bf16)w1[0]; f[5] = (__bf16)w1[1];
            f[6] = (__bf16)w1[2]; f[7] = (__bf16)w1[3];
            wfrag[ks] = f;
        }
    }

    const float bias_v = conv_b[tid & 63];   // epilogue: o = tid&63, b = wave

    for (int g = blockIdx.x; g < NGROUPS; g += gridDim.x) {
        const int v0 = g * NV;
        __syncthreads();  // A_lds free (prev epilogue done)

        // ---------------- phase 1: gather + interpolate (per-wave) ----------
#pragma unroll
        for (int vv2 = 0; vv2 < 2; ++vv2) {
            const int vv = wave * 2 + vv2;
            const int v = v0 + vv;
            if (v < VN) {                                   // wave-uniform
                const int* idxv = index + (size_t)v * KN;   // -> s_load
                const float* am = itp_mat + (size_t)v * (KN * KN);
                const int row = vv * 4 + (lane >> 4);       // b = t>>6 = lane>>4
                __bf16* rowp = (__bf16*)(smem + row * LDA_B) + (lane & 15) * 36;
#pragma unroll
                for (int half = 0; half < 2; ++half) {
                    // lane covers t = lane*4 + (2*half .. 2*half+1): one dword/neighbor
                    bf16x2 g2[KN];
#pragma unroll
                    for (int k = 0; k < KN; ++k) {
                        const int nb = idxv[k];
                        g2[k] = *(const bf16x2*)(xt + (size_t)nb * 256 + lane * 4 + half * 2);
                    }
                    float s0[KN], s1[KN];
#pragma unroll
                    for (int j = 0; j < KN; ++j) { s0[j] = 0.f; s1[j] = 0.f; }
#pragma unroll
                    for (int k = 0; k < KN; ++k) {
                        const float ga = (float)g2[k][0];
                        const float gb = (float)g2[k][1];
#pragma unroll
                        for (int j = 0; j < KN; ++j) {
                            const float a = am[k * KN + j];
                            s0[j] += ga * a;
                            s1[j] += gb * a;
                        }
                    }
                    __bf16 tmp[18];
#pragma unroll
                    for (int j = 0; j < KN; ++j) { tmp[j] = (__bf16)s0[j]; tmp[9 + j] = (__bf16)s1[j]; }
                    __bf16* wp = rowp + half * 18;
#pragma unroll
                    for (int i = 0; i < 18; ++i) wp[i] = tmp[i];
                }
            }
        }
        __syncthreads();

        // ---------------- phase 2: MFMA conv ----------------
        f32x4 acc0 = {0.f, 0.f, 0.f, 0.f};
        f32x4 acc1 = {0.f, 0.f, 0.f, 0.f};
        {
            const char* arow0 = smem + l16 * LDA_B + kb * 2;        // rows 0..15
            const char* arow1 = arow0 + 16 * LDA_B;                 // rows 16..31
#pragma unroll
            for (int ks = 0; ks < NKS; ++ks) {
                bf16x8 a0 = *(const bf16x8*)(arow0 + ks * 64);
                bf16x8 a1 = *(const bf16x8*)(arow1 + ks * 64);
                acc0 = __builtin_amdgcn_mfma_f32_16x16x32_bf16(a0, wfrag[ks], acc0, 0, 0, 0);
                acc1 = __builtin_amdgcn_mfma_f32_16x16x32_bf16(a1, wfrag[ks], acc1, 0, 0, 0);
            }
        }
        __syncthreads();  // done reading A_lds

        // ---------------- C staging through LDS ----------------
        float* c_lds = (float*)smem;   // [32 rows][65] f32 = 8320 B
        {
            const int ocol = wave * 16 + l16;
#pragma unroll
            for (int r = 0; r < 4; ++r) {
                c_lds[(g4 * 4 + r) * 65 + ocol]        = acc0[r];
                c_lds[(16 + g4 * 4 + r) * 65 + ocol]   = acc1[r];
            }
        }
        __syncthreads();

        // ---------------- epilogue ----------------
        {
            float vals[NV];
#pragma unroll
            for (int vv = 0; vv < NV; ++vv)
                vals[vv] = c_lds[(vv * 4 + wave) * 65 + (tid & 63)] + bias_v;
            float* op = out + (size_t)tid * VN + v0;   // out[(b*64+o)*V + v], tid == b*64+o
            const int vleft = VN - v0;
            if (vleft >= NV) {
                *(f32x2*)(op + 0) = {vals[0], vals[1]};
                *(f32x2*)(op + 2) = {vals[2], vals[3]};
                *(f32x2*)(op + 4) = {vals[4], vals[5]};
                *(f32x2*)(op + 6) = {vals[6], vals[7]};
            } else {
                for (int vv = 0; vv < vleft; ++vv) op[vv] = vals[vv];
            }
        }
    }
}

// ---------------------------------------------------------------------------
extern "C" void kernel_launch(void* const* d_in, const int* in_sizes, int n_in,
                              void* d_out, int out_size, void* d_ws, size_t ws_size,
                              hipStream_t stream) {
    const float* x       = (const float*)d_in[0];
    const int*   index   = (const int*)d_in[1];
    const float* itp_mat = (const float*)d_in[2];
    const float* conv_w  = (const float*)d_in[3];
    const float* conv_b  = (const float*)d_in[4];
    float* out = (float*)d_out;

    __bf16* xt = (__bf16*)d_ws;   // VN*256*2 = 20,972,544 B of workspace

    dim3 tgrid((VN + 63) / 64, 4, 1);
    k_transpose<<<tgrid, 256, 0, stream>>>(x, xt);
    k_fused<<<GRID_FUSED, 256, 0, stream>>>(xt, index, itp_mat, conv_w, conv_b, out);
}

// Round 3
// 112.484 us; speedup vs baseline: 2.7426x; 2.7426x over previous
//
#include <hip/hip_runtime.h>
#include <hip/hip_bf16.h>

// Problem constants (SelectSphereConv, graph level 6)
#define VN 40962
#define KN 9
#define KK 576            // CN*KN, GEMM reduction dim
#define NKS 18            // KK/32 K-steps for 16x16x32 MFMA
#define NV 8              // vertices per block-group
#define NGROUPS 5121      // ceil(VN/NV)
#define GRID_FUSED 1024
#define LDA_B 1168        // A-tile row stride bytes: 576*2 + 16 pad

typedef float f32x4 __attribute__((ext_vector_type(4)));
typedef __bf16 bf16x8 __attribute__((ext_vector_type(8)));
typedef __bf16 bf16x2 __attribute__((ext_vector_type(2)));

// ---------------------------------------------------------------------------
// Kernel 1: transpose x [256(t=b*64+c), V] f32 -> x_t [V, 256] bf16
// ---------------------------------------------------------------------------
__global__ __launch_bounds__(256) void k_transpose(const float* __restrict__ x,
                                                   __bf16* __restrict__ xt) {
    __shared__ __bf16 tile[64][65];
    const int v0 = blockIdx.x * 64;
    const int t0 = blockIdx.y * 64;
    const int lane = threadIdx.x & 63;
    const int sub = threadIdx.x >> 6;  // 0..3

#pragma unroll
    for (int r = 0; r < 16; ++r) {
        const int t = t0 + r * 4 + sub;
        const int v = v0 + lane;
        float val = (v < VN) ? x[(size_t)t * VN + v] : 0.f;  // coalesced
        tile[r * 4 + sub][lane] = (__bf16)val;
    }
    __syncthreads();
#pragma unroll
    for (int r = 0; r < 16; ++r) {
        const int vv = r * 4 + sub;
        const int v = v0 + vv;
        if (v < VN) xt[(size_t)v * 256 + t0 + lane] = tile[lane][vv];  // coalesced
    }
}

// ---------------------------------------------------------------------------
// Kernel 2: fused gather + interpolate (VALU) + conv (MFMA), pipelined.
//   Gather: thread t owns dword d=t&127 (channels 2c2,2c2+1 of batch d>>5)
//           of vertex 2p+(t>>7); 36 dwords/group prefetched one group ahead.
//   A-tile: rows r = vv*4+b (32), cols k = c*9+j (576), bf16 in LDS.
//   MFMA:   acc = mfma(Wfrag, Afrag): D row = o (within wave's 16), col = (vv,b).
//   Stores: deferred to next iteration top (drain hides under interp).
//   Raw barriers (lgkmcnt-only waits) keep prefetch loads in flight.
// ---------------------------------------------------------------------------
__global__ __launch_bounds__(256) void k_fused(const __bf16* __restrict__ xt,
                                               const int* __restrict__ index,
                                               const float* __restrict__ itp_mat,
                                               const float* __restrict__ conv_w,
                                               const float* __restrict__ conv_b,
                                               float* __restrict__ out) {
    __shared__ char smem[32 * LDA_B];  // 37376 B A-tile

    const int tid  = threadIdx.x;
    const int lane = tid & 63;
    const int wave = tid >> 6;
    const int l16  = lane & 15;
    const int g4   = lane >> 4;     // 0..3
    const int kb   = g4 * 8;        // k-base within a 32-wide K-step

    // ---- W fragments (MFMA operand A): 18 ksteps x 8 bf16 = 72 VGPR ----
    bf16x8 wfrag[NKS];
    {
        const int o = wave * 16 + l16;
        const float* wrow = conv_w + (size_t)o * KK;
#pragma unroll
        for (int ks = 0; ks < NKS; ++ks) {
            f32x4 w0 = *(const f32x4*)(wrow + ks * 32 + kb);
            f32x4 w1 = *(const f32x4*)(wrow + ks * 32 + kb + 4);
            bf16x8 f;
            f[0] = (__bf16)w0[0]; f[1] = (__bf16)w0[1];
            f[2] = (__bf16)w0[2]; f[3] = (__bf16)w0[3];
            f[4] = (__bf16)w1[0]; f[5] = (__bf16)w1[1];
            f[6] = (__bf16)w1[2]; f[7] = (__bf16)w1[3];
            wfrag[ks] = f;
        }
    }

    // ---- store-side constants: D col = l16 -> (b = l16&3, vv = l16>>2) ----
    const int bs   = l16 & 3;
    const int vvs  = l16 >> 2;          // acc0: vv = vvs; acc1: vv = vvs+4
    const int o_b  = wave * 16 + g4 * 4;
    const f32x4 bias4 = *(const f32x4*)(conv_b + o_b);      // o = o_b + r
    float* const orow_base = out + (size_t)((bs << 6) + o_b) * VN;

    // ---- gather-side constants ----
    const int d    = tid & 127;         // dword within 512-B x_t row
    const int half = tid >> 7;          // vertex parity (wave-uniform)
    const int bg   = d >> 5;            // batch of this dword
    const int c2   = d & 31;            // channel pair
    const uint* const xt2 = (const uint*)xt;

    // ---- prologue: prefetch gathers for first group ----
    uint pf[4][KN];
    {
        const int g0 = blockIdx.x;
#pragma unroll
        for (int p = 0; p < 4; ++p) {
            const int vraw = g0 * NV + 2 * p + half;
            const int vp = __builtin_amdgcn_readfirstlane(vraw < VN ? vraw : VN - 1);
            const int* idxp = index + (size_t)vp * KN;
#pragma unroll
            for (int k = 0; k < KN; ++k)
                pf[p][k] = xt2[(size_t)idxp[k] * 128 + d];
        }
    }

    bool have = false;
    int vprev = 0;
    f32x4 sacc0, sacc1;

    for (int g = blockIdx.x; g < NGROUPS; g += GRID_FUSED) {
        const int v0 = g * NV;
        const int gnext = (g + GRID_FUSED < NGROUPS) ? (g + GRID_FUSED) : (NGROUPS - 1);

        // ---- phase 0: deferred stores of previous group's output ----
        if (have) {
#pragma unroll
            for (int r = 0; r < 4; ++r) {
                float* orr = orow_base + (size_t)r * VN + vprev;
                if (vprev + vvs < VN)     orr[vvs]     = sacc0[r] + bias4[r];
                if (vprev + vvs + 4 < VN) orr[vvs + 4] = sacc1[r] + bias4[r];
            }
        }

        // ---- phase 1: interpolate from prefetched regs, write A-tile,
        //      reload pf for next group (flies across both barriers) ----
#pragma unroll
        for (int p = 0; p < 4; ++p) {
            const int vraw = v0 + 2 * p + half;
            const int vp = __builtin_amdgcn_readfirstlane(vraw < VN ? vraw : VN - 1);
            const float* am = itp_mat + (size_t)vp * (KN * KN);   // scalar path
            float run[18];
#pragma unroll
            for (int j = 0; j < 18; ++j) run[j] = 0.f;
#pragma unroll
            for (int k = 0; k < KN; ++k) {
                const bf16x2 t = __builtin_bit_cast(bf16x2, pf[p][k]);
                const float ga = (float)t[0];
                const float gb = (float)t[1];
#pragma unroll
                for (int j = 0; j < KN; ++j) {
                    const float a = am[k * KN + j];
                    run[j]     += ga * a;   // channel 2*c2
                    run[9 + j] += gb * a;   // channel 2*c2+1
                }
            }
            // contiguous 36 B at column (2*c2)*9; banks 9*c2+i mod 32: conflict-free
            char* wp = smem + (size_t)((2 * p + half) * 4 + bg) * LDA_B + 36 * c2;
#pragma unroll
            for (int i = 0; i < 9; ++i) {
                bf16x2 hv = { (__bf16)run[2 * i], (__bf16)run[2 * i + 1] };
                *(bf16x2*)(wp + 4 * i) = hv;
            }
            // prefetch this p-slot for the next group
            const int vnraw = gnext * NV + 2 * p + half;
            const int vnp = __builtin_amdgcn_readfirstlane(vnraw < VN ? vnraw : VN - 1);
            const int* idxn = index + (size_t)vnp * KN;
#pragma unroll
            for (int k = 0; k < KN; ++k)
                pf[p][k] = xt2[(size_t)idxn[k] * 128 + d];
        }

        asm volatile("s_waitcnt lgkmcnt(0)" ::: "memory");  // A-tile writes visible
        __builtin_amdgcn_s_barrier();

        // ---- phase 2: MFMA (W as operand A, itp-tile as operand B) ----
        f32x4 acc0 = {0.f, 0.f, 0.f, 0.f};
        f32x4 acc1 = {0.f, 0.f, 0.f, 0.f};
        {
            const char* arow0 = smem + l16 * LDA_B + kb * 2;   // tile rows 0..15
            const char* arow1 = arow0 + 16 * LDA_B;            // tile rows 16..31
#pragma unroll
            for (int ks = 0; ks < NKS; ++ks) {
                bf16x8 a0 = *(const bf16x8*)(arow0 + ks * 64);
                bf16x8 a1 = *(const bf16x8*)(arow1 + ks * 64);
                acc0 = __builtin_amdgcn_mfma_f32_16x16x32_bf16(wfrag[ks], a0, acc0, 0, 0, 0);
                acc1 = __builtin_amdgcn_mfma_f32_16x16x32_bf16(wfrag[ks], a1, acc1, 0, 0, 0);
            }
        }

        asm volatile("s_waitcnt lgkmcnt(0)" ::: "memory");  // A-tile reads done
        __builtin_amdgcn_s_barrier();

        sacc0 = acc0; sacc1 = acc1;
        have = true; vprev = v0;
    }

    // ---- final deferred stores ----
    if (have) {
#pragma unroll
        for (int r = 0; r < 4; ++r) {
            float* orr = orow_base + (size_t)r * VN + vprev;
            if (vprev + vvs < VN)     orr[vvs]     = sacc0[r] + bias4[r];
            if (vprev + vvs + 4 < VN) orr[vvs + 4] = sacc1[r] + bias4[r];
        }
    }
}

// ---------------------------------------------------------------------------
extern "C" void kernel_launch(void* const* d_in, const int* in_sizes, int n_in,
                              void* d_out, int out_size, void* d_ws, size_t ws_size,
                              hipStream_t stream) {
    const float* x       = (const float*)d_in[0];
    const int*   index   = (const int*)d_in[1];
    const float* itp_mat = (const float*)d_in[2];
    const float* conv_w  = (const float*)d_in[3];
    const float* conv_b  = (const float*)d_in[4];
    float* out = (float*)d_out;

    __bf16* xt = (__bf16*)d_ws;   // VN*256*2 = 20,972,544 B of workspace

    dim3 tgrid((VN + 63) / 64, 4, 1);
    k_transpose<<<tgrid, 256, 0, stream>>>(x, xt);
    k_fused<<<GRID_FUSED, 256, 0, stream>>>(xt, index, itp_mat, conv_w, conv_b, out);
}